// Round 6
// baseline (465.434 us; speedup 1.0000x reference)
//
#include <hip/hip_runtime.h>

// Sliding-window CMVN, K=301, reflect pad. feats [64,8192,80] fp32.
//
// R5: latency-bound diagnosis (248us, 2.57 TB/s, VALUBusy 9%, VGPR=36).
// VGPR=36 => compiler kept ~1 load in flight per wave; each wave serialized
// ~181 queue-inflated (~3K cy) load latencies. Fix = explicit MLP:
//  - Phase 3: ping-pong register double-buffer, 4 outputs/group, 12 named
//    f32x4 per buffer (x, xl, xt). 12-24 loads in flight per wave.
//  - __launch_bounds__(640) only (the old ",5" capped VGPR at ~102).
//  - Phase-2 partial sums fully unrolled for load batching.
//  - Bijective XCD swizzle: same-b superchunks land on one XCD.
// Kept from R4 (verified passing): coop seg-sum init in LDS, G=32,
// 640 thr = 32 slots x 20 float4-cols, nontemporal stores.

typedef float f32x4 __attribute__((ext_vector_type(4)));

namespace {
constexpr int K   = 301;
constexpr int PAD = 150;
constexpr float EPS = 1e-8f;
constexpr int Bb = 64;
constexpr int T  = 8192;
constexpr int C  = 80;
constexpr int C4 = 20;                 // float4 columns
constexpr int G  = 32;                 // outputs per thread
constexpr int SLOTS = 32;              // time sub-chunks per block
constexpr int THREADS = SLOTS * C4;    // 640 (10 waves)
constexpr int SUPER = SLOTS * G;       // 1024 steps per block
constexpr int NSUPER = T / SUPER;      // 8
constexpr int NSEG = SLOTS + 8;        // 40 segs; absolute seg = j-4
constexpr float INVK = 1.0f / (float)K;
}

__device__ __forceinline__ int reflect(int u) {
    u = (u < 0) ? -u : u;
    return (u >= T) ? (2 * (T - 1) - u) : u;
}
__device__ __forceinline__ int rh(int u) {   // high-side reflect only
    return (u >= T) ? (2 * (T - 1) - u) : u;
}
__device__ __forceinline__ int rl(int u) {   // low-side reflect only
    return (u < 0) ? -u : u;
}

// ---- phase-3 pipeline macros (named vars only; no runtime-indexed arrays) --
#define LD(t) (*reinterpret_cast<const f32x4*>(row + (size_t)(t) * C))

#define GLOAD(P, tb) do {                                                  \
    P##x0 = LD(tb);            P##x1 = LD((tb) + 1);                       \
    P##x2 = LD((tb) + 2);      P##x3 = LD((tb) + 3);                       \
    P##l0 = LD(rh((tb) + 151)); P##l1 = LD(rh((tb) + 152));                \
    P##l2 = LD(rh((tb) + 153)); P##l3 = LD(rh((tb) + 154));                \
    P##t0 = LD(rl((tb) - 150)); P##t1 = LD(rl((tb) - 149));                \
    P##t2 = LD(rl((tb) - 148)); P##t3 = LD(rl((tb) - 147));                \
} while (0)

#define STEP(px, pl, pt, t) do {                                           \
    f32x4 o;                                                               \
    { const float mu = S.x * INVK;                                         \
      const float var = fmaxf(fmaf(Q.x, INVK, -(mu * mu)), EPS);           \
      o.x = ((px).x - mu) * rsqrtf(var); }                                 \
    { const float mu = S.y * INVK;                                         \
      const float var = fmaxf(fmaf(Q.y, INVK, -(mu * mu)), EPS);           \
      o.y = ((px).y - mu) * rsqrtf(var); }                                 \
    { const float mu = S.z * INVK;                                         \
      const float var = fmaxf(fmaf(Q.z, INVK, -(mu * mu)), EPS);           \
      o.z = ((px).z - mu) * rsqrtf(var); }                                 \
    { const float mu = S.w * INVK;                                         \
      const float var = fmaxf(fmaf(Q.w, INVK, -(mu * mu)), EPS);           \
      o.w = ((px).w - mu) * rsqrtf(var); }                                 \
    __builtin_nontemporal_store(o,                                         \
        reinterpret_cast<f32x4*>(orow + (size_t)(t) * C));                 \
    S += (pl) - (pt);                                                      \
    Q.x += fmaf((pl).x, (pl).x, -((pt).x * (pt).x));                       \
    Q.y += fmaf((pl).y, (pl).y, -((pt).y * (pt).y));                       \
    Q.z += fmaf((pl).z, (pl).z, -((pt).z * (pt).z));                       \
    Q.w += fmaf((pl).w, (pl).w, -((pt).w * (pt).w));                       \
} while (0)

#define GCOMP(P, tb) do {                                                  \
    STEP(P##x0, P##l0, P##t0, (tb));                                       \
    STEP(P##x1, P##l1, P##t1, (tb) + 1);                                   \
    STEP(P##x2, P##l2, P##t2, (tb) + 2);                                   \
    STEP(P##x3, P##l3, P##t3, (tb) + 3);                                   \
} while (0)

__global__ __launch_bounds__(THREADS)
void cmvn_coop(const float* __restrict__ in, float* __restrict__ out) {
    __shared__ f32x4 segS[NSEG * C4];
    __shared__ f32x4 segQ[NSEG * C4];

    const int tid = threadIdx.x;
    // bijective XCD swizzle: all 8 superchunks of a batch-row b share an XCD
    const int kblk = blockIdx.x;
    const int b  = (kblk >> 6) * 8 + (kblk & 7);
    const int sc = (kblk & 63) >> 3;
    const int B0 = sc * SUPER;
    const float* __restrict__ base_in = in + (size_t)b * T * C;

    // ---- phase 1: 32-wide segment sums for segs j=0..39 (abs j-4) ----
    for (int task = tid; task < NSEG * C4; task += THREADS) {
        const int j  = task / C4;
        const int cc = task % C4;
        const float* __restrict__ r = base_in + cc * 4;
        const int s0 = B0 + (j - 4) * G;
        f32x4 s = {0.f,0.f,0.f,0.f}, q = {0.f,0.f,0.f,0.f};
        #pragma unroll 8
        for (int k = 0; k < G; ++k) {
            const int u = reflect(s0 + k);
            const f32x4 v = *reinterpret_cast<const f32x4*>(r + (size_t)u * C);
            s += v;
            q.x = fmaf(v.x, v.x, q.x); q.y = fmaf(v.y, v.y, q.y);
            q.z = fmaf(v.z, v.z, q.z); q.w = fmaf(v.w, v.w, q.w);
        }
        segS[task] = s;
        segQ[task] = q;
    }
    __syncthreads();

    // ---- phase 2: per-thread init of window sums at t0 ----
    const int c4   = tid % C4;
    const int slot = tid / C4;
    const int t0   = B0 + slot * G;
    const float* __restrict__ row  = base_in + c4 * 4;
    float* __restrict__       orow = out + (size_t)b * T * C + c4 * 4;

    f32x4 S = {0.f,0.f,0.f,0.f}, Q = {0.f,0.f,0.f,0.f};

    const bool interior = (t0 >= PAD) && (t0 + PAD <= T - 1);
    if (interior) {
        // full segs cover [t0-128, t0+127] = j slot..slot+7
        #pragma unroll
        for (int jj = 0; jj < 8; ++jj) {
            S += segS[(slot + jj) * C4 + c4];
            Q += segQ[(slot + jj) * C4 + c4];
        }
        // tail partial [t0-150, t0-129] (22) + head partial [t0+128, t0+150] (23)
        #pragma unroll
        for (int u = t0 - PAD; u <= t0 - 129; ++u) {
            const f32x4 v = *reinterpret_cast<const f32x4*>(row + (size_t)u * C);
            S += v;
            Q.x = fmaf(v.x, v.x, Q.x); Q.y = fmaf(v.y, v.y, Q.y);
            Q.z = fmaf(v.z, v.z, Q.z); Q.w = fmaf(v.w, v.w, Q.w);
        }
        #pragma unroll
        for (int u = t0 + 128; u <= t0 + PAD; ++u) {
            const f32x4 v = *reinterpret_cast<const f32x4*>(row + (size_t)u * C);
            S += v;
            Q.x = fmaf(v.x, v.x, Q.x); Q.y = fmaf(v.y, v.y, Q.y);
            Q.z = fmaf(v.z, v.z, Q.z); Q.w = fmaf(v.w, v.w, Q.w);
        }
    } else {
        // edge slow path (~3.5% of threads): naive reflect init
        for (int u = t0 - PAD; u <= t0 + PAD; ++u) {
            const int ru = reflect(u);
            const f32x4 v = *reinterpret_cast<const f32x4*>(row + (size_t)ru * C);
            S += v;
            Q.x = fmaf(v.x, v.x, Q.x); Q.y = fmaf(v.y, v.y, Q.y);
            Q.z = fmaf(v.z, v.z, Q.z); Q.w = fmaf(v.w, v.w, Q.w);
        }
    }

    // ---- phase 3: ping-pong register-pipelined stream, 8 groups of 4 ----
    f32x4 Ax0, Ax1, Ax2, Ax3, Al0, Al1, Al2, Al3, At0, At1, At2, At3;
    f32x4 Bx0, Bx1, Bx2, Bx3, Bl0, Bl1, Bl2, Bl3, Bt0, Bt1, Bt2, Bt3;

    GLOAD(A, t0);
    GLOAD(B, t0 + 4);
    for (int p = 0; p < 3; ++p) {
        const int tb = t0 + 8 * p;
        GCOMP(A, tb);
        GLOAD(A, tb + 8);
        GCOMP(B, tb + 4);
        GLOAD(B, tb + 12);
    }
    GCOMP(A, t0 + 24);
    GCOMP(B, t0 + 28);
}

extern "C" void kernel_launch(void* const* d_in, const int* in_sizes, int n_in,
                              void* d_out, int out_size, void* d_ws, size_t ws_size,
                              hipStream_t stream) {
    const float* in = (const float*)d_in[0];
    float* out = (float*)d_out;
    constexpr int blocks = Bb * NSUPER;   // 512
    cmvn_coop<<<blocks, THREADS, 0, stream>>>(in, out);
}

// Round 9
// 386.145 us; speedup vs baseline: 1.2053x; 1.2053x over previous
//
#include <hip/hip_runtime.h>

// Sliding-window CMVN, K=301, reflect pad. feats [64,8192,80] fp32.
//
// R6 architecture (2nd resubmit; infra failures R7/R8, kernel never ran):
// LDS cumsum ring + chunked streaming. Evidence R3-R5: dur pinned ~250us
// regardless of traffic/occupancy; per-thread dependent global loads are
// the wall. Fix: block-local prefix sums in LDS; all window reads become
// LDS reads; global reads become a bulk 1-load-per-thread-per-chunk stream
// kept in flight ACROSS raw s_barriers (no __syncthreads vmcnt(0) drain).
//
// Block = (batch b, 2048-step T-segment, 40-channel half): 512 blocks.
// Per 64-step chunk j (38 chunks incl. 2x192 halo):
//   1. ds_write staged reg (chunk j), lgkmcnt(0), raw barrier
//   2. issue global load chunk j+2 (stays in flight across barriers)
//   3. wave w scans column w (64 lanes = 64 steps, __shfl_up inclusive,
//      + per-wave carry), writes cs/csq ring; lgkmcnt(0), raw barrier
//   4. compute outputs chunk j-6: S=cs[L+150]-cs[L-151], Q likewise,
//      x=cs[L]-cs[L-1]; 6 ds_reads + ~40 VALU + 1 NT store.
// Verified: LAG=6 minimal (LAG*64 >= HALO+150=342); ring span 407 <= 409;
// phase4(j) reads vs phase3(j+1) writes separated by phase-1 barrier.

typedef float f32x4 __attribute__((ext_vector_type(4)));

namespace {
constexpr int K = 301;
constexpr int PAD = 150;
constexpr float EPS = 1e-8f;
constexpr int Bb = 64, T = 8192, C = 80;
constexpr int COLS = 10;            // f32x4 columns per block (40 ch)
constexpr int CH = 64;              // chunk length (steps)
constexpr int STRIP = 2048;         // output steps per block
constexpr int HALO = 192;           // 3 chunks each side
constexpr int NCHUNK = (STRIP + 2 * HALO) / CH;  // 38
constexpr int LAG = 6;              // scan-ahead chunks before compute
constexpr int RING = 409;           // ring steps (>=407, odd)
constexpr int THREADS = 640;        // 10 waves = 10 columns
constexpr float INVK = 1.0f / 301.0f;
// LDS layout in f32x4 units: csS [COLS][RING], csQ [COLS][RING], staging
constexpr int CSQ_OFF = COLS * RING;          // 4090
constexpr int STG_OFF = 2 * COLS * RING;      // 8180
constexpr int STG_STRIDE = 11;                // padded row (bank spread)
constexpr int LDS_F4 = STG_OFF + CH * STG_STRIDE;   // 8884
constexpr int LDS_BYTES = LDS_F4 * 16;              // 142,144 B
}

__device__ __forceinline__ int reflectT(int t) {
    t = (t < 0) ? -t : t;
    return (t >= T) ? (2 * (T - 1) - t) : t;
}

__device__ __forceinline__ f32x4 wscan_incl(f32x4 v, int lane) {
    #pragma unroll
    for (int d = 1; d < 64; d <<= 1) {
        f32x4 u;
        u.x = __shfl_up(v.x, d, 64);
        u.y = __shfl_up(v.y, d, 64);
        u.z = __shfl_up(v.z, d, 64);
        u.w = __shfl_up(v.w, d, 64);
        if (lane >= d) v += u;
    }
    return v;
}

__device__ __forceinline__ f32x4 bcast63(f32x4 v) {
    f32x4 r;
    r.x = __shfl(v.x, 63, 64);
    r.y = __shfl(v.y, 63, 64);
    r.z = __shfl(v.z, 63, 64);
    r.w = __shfl(v.w, 63, 64);
    return r;
}

__global__ __launch_bounds__(THREADS)
void cmvn_cs(const float* __restrict__ in, float* __restrict__ out) {
    extern __shared__ f32x4 lds[];
    const int tid = threadIdx.x;
    const int bid = blockIdx.x;
    // bid = chalf*256 + b*4 + seg : chalf-siblings differ by 256 = 0 mod 8
    // -> same XCD -> L2 merges their shared half-lines.
    const int chalf = bid >> 8;
    const int b     = (bid & 255) >> 2;
    const int seg   = bid & 3;
    const int seg0  = seg * STRIP;

    const float* __restrict__ gin  = in  + (size_t)b * T * C + chalf * 40;
    float* __restrict__       gout = out + (size_t)b * T * C + chalf * 40;

    const int s_step = tid / COLS;       // staging & compute: step 0..63
    const int s_col  = tid % COLS;       // column 0..9
    const int w      = tid >> 6;         // scan: wave = column
    const int lane   = tid & 63;         // scan: step within chunk

    // per-wave cumsum carries (uniform across wave)
    f32x4 prevS = {0.f, 0.f, 0.f, 0.f};
    f32x4 prevQ = {0.f, 0.f, 0.f, 0.f};

    auto gload = [&](int j) -> f32x4 {
        const int tg = reflectT(seg0 - HALO + j * CH + s_step);
        return *reinterpret_cast<const f32x4*>(gin + (size_t)tg * C + s_col * 4);
    };

    // depth-2 load pipeline
    f32x4 Ra = gload(0);
    f32x4 Rb = gload(1);

    const int stg_w = STG_OFF + s_step * STG_STRIDE + s_col;  // staging write
    const int stg_r = STG_OFF + lane * STG_STRIDE + w;        // scan read

    int jb = 0;            // (j*CH) % RING, incremental
    int ob = HALO;         // output-chunk ring base, incremental (valid at j>=LAG)

    for (int j = 0; j < NCHUNK; ++j) {
        // ---- phase 1: stage chunk j (compiler emits counted vmcnt for Ra) --
        lds[stg_w] = Ra;
        asm volatile("s_waitcnt lgkmcnt(0)" ::: "memory");
        __builtin_amdgcn_s_barrier();
        __builtin_amdgcn_sched_barrier(0);

        // ---- phase 2: issue chunk j+2 load (in flight across barriers) ----
        const int jn = (j + 2 < NCHUNK) ? (j + 2) : (NCHUNK - 1);
        f32x4 Rn = gload(jn);

        // ---- phase 3: wave-scan chunk j, column w ----
        const f32x4 xv = lds[stg_r];
        f32x4 xq;
        xq.x = xv.x * xv.x; xq.y = xv.y * xv.y;
        xq.z = xv.z * xv.z; xq.w = xv.w * xv.w;
        const f32x4 sS = wscan_incl(xv, lane);
        const f32x4 sQ = wscan_incl(xq, lane);
        int wi = jb + lane; if (wi >= RING) wi -= RING;
        lds[w * RING + wi]           = prevS + sS;
        lds[CSQ_OFF + w * RING + wi] = prevQ + sQ;
        prevS += bcast63(sS);
        prevQ += bcast63(sQ);
        asm volatile("s_waitcnt lgkmcnt(0)" ::: "memory");
        __builtin_amdgcn_s_barrier();
        __builtin_amdgcn_sched_barrier(0);

        // ---- phase 4: compute outputs for chunk j-LAG ----
        if (j >= LAG) {
            int m0 = ob + s_step; if (m0 >= RING) m0 -= RING;        // L
            int i1 = m0 + PAD;     if (i1 >= RING) i1 -= RING;       // L+150
            int i2 = m0 - (PAD + 1); if (i2 < 0) i2 += RING;         // L-151
            int i4 = m0 - 1;       if (i4 < 0) i4 += RING;           // L-1
            const int cb = s_col * RING;
            const f32x4 csA = lds[cb + i1];
            const f32x4 csB = lds[cb + i2];
            const f32x4 cqA = lds[CSQ_OFF + cb + i1];
            const f32x4 cqB = lds[CSQ_OFF + cb + i2];
            const f32x4 csX = lds[cb + m0];
            const f32x4 csM = lds[cb + i4];
            const f32x4 S = csA - csB;
            const f32x4 Q = cqA - cqB;
            const f32x4 x = csX - csM;
            f32x4 o;
            {
                const float mu = S.x * INVK;
                const float var = fmaxf(fmaf(Q.x, INVK, -(mu * mu)), EPS);
                o.x = (x.x - mu) * rsqrtf(var);
            }
            {
                const float mu = S.y * INVK;
                const float var = fmaxf(fmaf(Q.y, INVK, -(mu * mu)), EPS);
                o.y = (x.y - mu) * rsqrtf(var);
            }
            {
                const float mu = S.z * INVK;
                const float var = fmaxf(fmaf(Q.z, INVK, -(mu * mu)), EPS);
                o.z = (x.z - mu) * rsqrtf(var);
            }
            {
                const float mu = S.w * INVK;
                const float var = fmaxf(fmaf(Q.w, INVK, -(mu * mu)), EPS);
                o.w = (x.w - mu) * rsqrtf(var);
            }
            const int t_out = seg0 + (j - LAG) * CH + s_step;
            __builtin_nontemporal_store(o,
                reinterpret_cast<f32x4*>(gout + (size_t)t_out * C + s_col * 4));
            ob += CH; if (ob >= RING) ob -= RING;
        }

        jb += CH; if (jb >= RING) jb -= RING;
        Ra = Rb; Rb = Rn;
    }
}

extern "C" void kernel_launch(void* const* d_in, const int* in_sizes, int n_in,
                              void* d_out, int out_size, void* d_ws, size_t ws_size,
                              hipStream_t stream) {
    const float* in = (const float*)d_in[0];
    float* out = (float*)d_out;
    // Raise dynamic-LDS cap. Persistent per-function attribute: the first
    // (non-captured correctness) call sets it; discard return defensively.
    (void)hipFuncSetAttribute(reinterpret_cast<const void*>(cmvn_cs),
                              hipFuncAttributeMaxDynamicSharedMemorySize,
                              LDS_BYTES);
    cmvn_cs<<<512, THREADS, LDS_BYTES, stream>>>(in, out);
}